// Round 7
// baseline (394.081 us; speedup 1.0000x reference)
//
#include <hip/hip_runtime.h>

#define D 128
#define HS_LD 136  // h-tile LDS stride (ushorts): 272B rows, 16B-aligned, 2-way conflicts only

using s8v = __attribute__((ext_vector_type(8))) short;
using f4v = __attribute__((ext_vector_type(4))) float;

__device__ __forceinline__ float bf2f(ushort u) {
  union { uint i; float f; } v; v.i = ((uint)u) << 16; return v.f;
}
__device__ __forceinline__ ushort f2bf(float f) {
  union { float f; uint i; } v; v.f = f;
  uint b = v.i;
  return (ushort)((b + 0x7fffu + ((b >> 16) & 1u)) >> 16);
}

// ---------------------------------------------------------------------------
// megaA: blocks [0,2048) degpos | [2048,5248) xcvt | [5248,5312) LF=lw@fw |
//        [5312,5376) T1g = bf16T(gw1)
// ---------------------------------------------------------------------------
__global__ void megaA_kernel(const int* __restrict__ dst, int* __restrict__ ideg,
                             int* __restrict__ pos, int E,
                             const float* __restrict__ x, ushort* __restrict__ xb, long total,
                             const float* __restrict__ lw, const float* __restrict__ fw,
                             float* __restrict__ LF,
                             const float* __restrict__ gw1, ushort* __restrict__ T1g) {
  int b = blockIdx.x;
  if (b < 2048) {
    int i = b * 256 + threadIdx.x;
    int stride = 2048 * 256;
    for (int e = i; e < E; e += stride)
      pos[e] = atomicAdd(&ideg[dst[e]], 1);
  } else if (b < 5248) {
    long i = ((long)(b - 2048) * 256 + threadIdx.x) * 8;
    long stride = (long)3200 * 256 * 8;
    for (long t = i; t < total; t += stride) {
      float4 v0 = *(const float4*)(x + t);
      float4 v1 = *(const float4*)(x + t + 4);
      s8v u;
      u[0] = (short)f2bf(v0.x); u[1] = (short)f2bf(v0.y);
      u[2] = (short)f2bf(v0.z); u[3] = (short)f2bf(v0.w);
      u[4] = (short)f2bf(v1.x); u[5] = (short)f2bf(v1.y);
      u[6] = (short)f2bf(v1.z); u[7] = (short)f2bf(v1.w);
      *(s8v*)(xb + t) = u;
    }
  } else if (b < 5312) {
    int t = (b - 5248) * 256 + threadIdx.x;
    int r = t >> 7, c = t & 127;
    float s = 0.f;
#pragma unroll 8
    for (int k = 0; k < 128; ++k) s = fmaf(lw[r * 128 + k], fw[k * 128 + c], s);
    LF[r * 128 + c] = s;
  } else {
    int t = (b - 5312) * 256 + threadIdx.x;
    int k = t >> 7, c = t & 127;
    T1g[c * 128 + k] = f2bf(gw1[k * 128 + c]);
  }
}

// ---------------------------------------------------------------------------
// scanP: blocks [0,nb) scan1 | [nb,nb+64) M2i=iw2@LF | [nb+64,nb+128)
//        W2gT=bf16T(gw2@LF) | [nb+128] btot
// ---------------------------------------------------------------------------
__global__ void scanP_kernel(const int* __restrict__ deg, int* __restrict__ incl,
                             int* __restrict__ bsum, int n, int nb,
                             const float* __restrict__ iw2, const float* __restrict__ gw2,
                             const float* __restrict__ LF,
                             float* __restrict__ M2i, ushort* __restrict__ W2gT,
                             const float* __restrict__ gb2, const float* __restrict__ ib2,
                             const float* __restrict__ lb, const float* __restrict__ fw,
                             const float* __restrict__ fb, float* __restrict__ btot) {
  int b = blockIdx.x;
  if (b < nb) {
    __shared__ int tmp[256];
    int t = threadIdx.x;
    int i = b * 256 + t;
    int v = (i < n) ? deg[i] : 0;
    tmp[t] = v;
    __syncthreads();
#pragma unroll
    for (int off = 1; off < 256; off <<= 1) {
      int u = (t >= off) ? tmp[t - off] : 0;
      __syncthreads();
      tmp[t] += u;
      __syncthreads();
    }
    if (i < n) incl[i] = tmp[t];
    if (t == 255) bsum[b] = tmp[255];
  } else if (b < nb + 64) {
    int t = (b - nb) * 256 + threadIdx.x;
    int k = t >> 7, c = t & 127;
    float s = 0.f;
#pragma unroll 8
    for (int j = 0; j < 128; ++j) s = fmaf(iw2[k * 128 + j], LF[j * 128 + c], s);
    M2i[k * 128 + c] = s;
  } else if (b < nb + 128) {
    int t = (b - nb - 64) * 256 + threadIdx.x;
    int k = t >> 7, c = t & 127;
    float s = 0.f;
#pragma unroll 8
    for (int j = 0; j < 128; ++j) s = fmaf(gw2[k * 128 + j], LF[j * 128 + c], s);
    W2gT[c * 128 + k] = f2bf(s);
  } else if (threadIdx.x < 128) {
    int c = threadIdx.x;
    float s = fb[c];
#pragma unroll 8
    for (int j = 0; j < 128; ++j) {
      s = fmaf(gb2[j] + ib2[j], LF[j * 128 + c], s);
      s = fmaf(2.f * lb[j], fw[j * 128 + c], s);
    }
    btot[c] = s;
  }
}

// ---------------------------------------------------------------------------
// scan2F: block 0 scan2 | blocks [1,64] WginT=bf16T(iw1@M2i) | block 65 bgin
// ---------------------------------------------------------------------------
__global__ void scan2F_kernel(int* __restrict__ bsum, int nb,
                              const float* __restrict__ iw1, const float* __restrict__ M2i,
                              ushort* __restrict__ WginT,
                              const float* __restrict__ ib1, float* __restrict__ bgin) {
  int b = blockIdx.x;
  if (b == 0) {
    __shared__ int tmp[256];
    __shared__ int carry_s;
    int t = threadIdx.x;
    if (t == 0) carry_s = 0;
    __syncthreads();
    for (int base = 0; base < nb; base += 256) {
      int v = (base + t < nb) ? bsum[base + t] : 0;
      tmp[t] = v;
      __syncthreads();
#pragma unroll
      for (int off = 1; off < 256; off <<= 1) {
        int u = (t >= off) ? tmp[t - off] : 0;
        __syncthreads();
        tmp[t] += u;
        __syncthreads();
      }
      int inc = tmp[t] + carry_s;
      if (base + t < nb) bsum[base + t] = inc;
      __syncthreads();
      if (t == 255) carry_s = inc;
      __syncthreads();
    }
  } else if (b <= 64) {
    int t = (b - 1) * 256 + threadIdx.x;
    int k = t >> 7, c = t & 127;
    float s = 0.f;
#pragma unroll 8
    for (int j = 0; j < 128; ++j) s = fmaf(iw1[k * 128 + j], M2i[j * 128 + c], s);
    WginT[c * 128 + k] = f2bf(s);
  } else if (threadIdx.x < 128) {
    int c = threadIdx.x;
    float s = 0.f;
#pragma unroll 8
    for (int j = 0; j < 128; ++j) s = fmaf(ib1[j], M2i[j * 128 + c], s);
    bgin[c] = s;
  }
}

__global__ void scan3_kernel(const int* __restrict__ deg, const int* __restrict__ incl,
                             const int* __restrict__ bsum, int* __restrict__ rowptr,
                             float* __restrict__ dinv, int n, int E) {
  int i = blockIdx.x * 256 + threadIdx.x;
  if (i < n) {
    int carry = (blockIdx.x > 0) ? bsum[blockIdx.x - 1] : 0;
    int d = deg[i];
    rowptr[i] = incl[i] - d + carry;
    dinv[i] = rsqrtf((float)d + 1.0f);
  }
  if (i == 0) rowptr[n] = E;
}

// scatter (no atomics): cdata[rowptr[d]+pos[e]] = (src[e], dinv[src[e]])
__global__ void scatter_kernel(const int* __restrict__ src, const int* __restrict__ dst,
                               const int* __restrict__ rowptr, const int* __restrict__ pos,
                               const float* __restrict__ dinv,
                               int2* __restrict__ cdata, int E) {
  int i = blockIdx.x * blockDim.x + threadIdx.x;
  int stride = gridDim.x * blockDim.x;
  for (int e = i; e < E; e += stride) {
    int s = src[e];
    cdata[rowptr[dst[e]] + pos[e]] = make_int2(s, __float_as_int(dinv[s]));
  }
}

// ---------------------------------------------------------------------------
// gather A: wave halves on alternate edges, 4-deep MLP, cdata carries
// (src, dinv_src); shfl_xor(32) combine; ab[node][256] = [gcn | gin] bf16.
// ---------------------------------------------------------------------------
__global__ __launch_bounds__(256) void gatherA_kernel(
    const ushort* __restrict__ xb, const float* __restrict__ dinv,
    const int* __restrict__ rowptr, const int2* __restrict__ cd,
    ushort* __restrict__ ab, int n) {
  int nd = blockIdx.x * 4 + (threadIdx.x >> 6);
  if (nd >= n) return;
  int lane = threadIdx.x & 63;
  int half = lane >> 5;
  int hl = lane & 31;
  int beg = rowptr[nd], end = rowptr[nd + 1];
  float4 sg = make_float4(0.f, 0.f, 0.f, 0.f);
  float4 sc = make_float4(0.f, 0.f, 0.f, 0.f);
  int j = beg + half;
  for (; j + 6 < end; j += 8) {
    int2 c0 = cd[j], c1 = cd[j + 2], c2 = cd[j + 4], c3 = cd[j + 6];
    float w0 = __int_as_float(c0.y), w1 = __int_as_float(c1.y);
    float w2 = __int_as_float(c2.y), w3 = __int_as_float(c3.y);
    ushort4 v0 = *(const ushort4*)(xb + (long)c0.x * D + 4 * hl);
    ushort4 v1 = *(const ushort4*)(xb + (long)c1.x * D + 4 * hl);
    ushort4 v2 = *(const ushort4*)(xb + (long)c2.x * D + 4 * hl);
    ushort4 v3 = *(const ushort4*)(xb + (long)c3.x * D + 4 * hl);
    float a0 = bf2f(v0.x), a1 = bf2f(v0.y), a2 = bf2f(v0.z), a3 = bf2f(v0.w);
    sg.x += a0; sg.y += a1; sg.z += a2; sg.w += a3;
    sc.x = fmaf(w0, a0, sc.x); sc.y = fmaf(w0, a1, sc.y);
    sc.z = fmaf(w0, a2, sc.z); sc.w = fmaf(w0, a3, sc.w);
    a0 = bf2f(v1.x); a1 = bf2f(v1.y); a2 = bf2f(v1.z); a3 = bf2f(v1.w);
    sg.x += a0; sg.y += a1; sg.z += a2; sg.w += a3;
    sc.x = fmaf(w1, a0, sc.x); sc.y = fmaf(w1, a1, sc.y);
    sc.z = fmaf(w1, a2, sc.z); sc.w = fmaf(w1, a3, sc.w);
    a0 = bf2f(v2.x); a1 = bf2f(v2.y); a2 = bf2f(v2.z); a3 = bf2f(v2.w);
    sg.x += a0; sg.y += a1; sg.z += a2; sg.w += a3;
    sc.x = fmaf(w2, a0, sc.x); sc.y = fmaf(w2, a1, sc.y);
    sc.z = fmaf(w2, a2, sc.z); sc.w = fmaf(w2, a3, sc.w);
    a0 = bf2f(v3.x); a1 = bf2f(v3.y); a2 = bf2f(v3.z); a3 = bf2f(v3.w);
    sg.x += a0; sg.y += a1; sg.z += a2; sg.w += a3;
    sc.x = fmaf(w3, a0, sc.x); sc.y = fmaf(w3, a1, sc.y);
    sc.z = fmaf(w3, a2, sc.z); sc.w = fmaf(w3, a3, sc.w);
  }
  for (; j < end; j += 2) {
    int2 c0 = cd[j];
    float w0 = __int_as_float(c0.y);
    ushort4 v0 = *(const ushort4*)(xb + (long)c0.x * D + 4 * hl);
    float a0 = bf2f(v0.x), a1 = bf2f(v0.y), a2 = bf2f(v0.z), a3 = bf2f(v0.w);
    sg.x += a0; sg.y += a1; sg.z += a2; sg.w += a3;
    sc.x = fmaf(w0, a0, sc.x); sc.y = fmaf(w0, a1, sc.y);
    sc.z = fmaf(w0, a2, sc.z); sc.w = fmaf(w0, a3, sc.w);
  }
  sg.x += __shfl_xor(sg.x, 32); sg.y += __shfl_xor(sg.y, 32);
  sg.z += __shfl_xor(sg.z, 32); sg.w += __shfl_xor(sg.w, 32);
  sc.x += __shfl_xor(sc.x, 32); sc.y += __shfl_xor(sc.y, 32);
  sc.z += __shfl_xor(sc.z, 32); sc.w += __shfl_xor(sc.w, 32);

  ushort4 us = *(const ushort4*)(xb + (long)nd * D + 4 * hl);
  float x0 = bf2f(us.x), x1 = bf2f(us.y), x2 = bf2f(us.z), x3 = bf2f(us.w);
  float dd = dinv[nd];
  ushort4 o;
  if (half == 0) {
    o.x = f2bf(dd * (sc.x + dd * x0));
    o.y = f2bf(dd * (sc.y + dd * x1));
    o.z = f2bf(dd * (sc.z + dd * x2));
    o.w = f2bf(dd * (sc.w + dd * x3));
    *(ushort4*)(ab + (long)nd * 256 + 4 * hl) = o;
  } else {
    o.x = f2bf(x0 + sg.x);
    o.y = f2bf(x1 + sg.y);
    o.z = f2bf(x2 + sg.z);
    o.w = f2bf(x3 + sg.w);
    *(ushort4*)(ab + (long)nd * 256 + 128 + 4 * hl) = o;
  }
}

// ---------------------------------------------------------------------------
// gemm1': y=0 (GCN): h = relu(Agcn@T1g^T + gb1); p1' = dinv_row * (h @ W2gT^T).
//         y=1 (GIN): p2 = Agin@WginT^T + bgin.
// Output pq[node][256] = [p1' | p2] bf16.
// ---------------------------------------------------------------------------
__global__ __launch_bounds__(256) void gemm1_kernel(
    const ushort* __restrict__ ab,
    const ushort* __restrict__ T1g, const ushort* __restrict__ WginT,
    const ushort* __restrict__ W2gT,
    const float* __restrict__ gb1, const float* __restrict__ bgin,
    const float* __restrict__ dinv,
    ushort* __restrict__ pq, int n) {
  __shared__ ushort Ws[128 * 128];
  __shared__ ushort Hs[128 * HS_LD];
  const int y = blockIdx.y;
  const int tid = threadIdx.x;
  const int wave = tid >> 6, lane = tid & 63;
  const int rlo = lane & 15, khi = lane >> 4;
  const int rb = blockIdx.x * 128 + wave * 32;

  s8v a[2][4];
#pragma unroll
  for (int rt = 0; rt < 2; ++rt) {
    int row = rb + rt * 16 + rlo;
    row = row < n ? row : n - 1;
    const ushort* p = ab + (long)row * 256 + y * 128 + khi * 8;
#pragma unroll
    for (int ks = 0; ks < 4; ++ks) a[rt][ks] = *(const s8v*)(p + ks * 32);
  }

  {
    const ushort* W = y ? WginT : T1g;
#pragma unroll
    for (int j = 0; j < 8; ++j) {
      int q = tid + 256 * j;
      int c = q >> 4, kc = q & 15;
      *(s8v*)&Ws[c * 128 + ((kc ^ (c & 7)) << 3)] = *(const s8v*)(W + c * 128 + kc * 8);
    }
  }
  __syncthreads();

  f4v acc[2][8];
#pragma unroll
  for (int rt = 0; rt < 2; ++rt)
#pragma unroll
    for (int ct = 0; ct < 8; ++ct) acc[rt][ct] = (f4v){0.f, 0.f, 0.f, 0.f};

#pragma unroll
  for (int ks = 0; ks < 4; ++ks) {
#pragma unroll
    for (int ct = 0; ct < 8; ++ct) {
      int c = ct * 16 + rlo;
      int kc = ks * 4 + khi;
      s8v b = *(const s8v*)&Ws[c * 128 + ((kc ^ (c & 7)) << 3)];
      acc[0][ct] = __builtin_amdgcn_mfma_f32_16x16x32_bf16(a[0][ks], b, acc[0][ct], 0, 0, 0);
      acc[1][ct] = __builtin_amdgcn_mfma_f32_16x16x32_bf16(a[1][ks], b, acc[1][ct], 0, 0, 0);
    }
  }

  if (y == 1) {
#pragma unroll
    for (int ct = 0; ct < 8; ++ct) {
      int col = ct * 16 + rlo;
      float bb = bgin[col];
#pragma unroll
      for (int rt = 0; rt < 2; ++rt) {
#pragma unroll
        for (int i = 0; i < 4; ++i) {
          int row = rb + rt * 16 + 4 * khi + i;
          if (row < n)
            pq[(long)row * 256 + 128 + col] = f2bf(acc[rt][ct][i] + bb);
        }
      }
    }
    return;
  }

  // ---- GCN stage 2 ----
  __syncthreads();
#pragma unroll
  for (int ct = 0; ct < 8; ++ct) {
    int col = ct * 16 + rlo;
    float bb = gb1[col];
#pragma unroll
    for (int rt = 0; rt < 2; ++rt) {
#pragma unroll
      for (int i = 0; i < 4; ++i) {
        int r = wave * 32 + rt * 16 + 4 * khi + i;
        Hs[r * HS_LD + col] = f2bf(fmaxf(acc[rt][ct][i] + bb, 0.f));
      }
    }
  }
#pragma unroll
  for (int j = 0; j < 8; ++j) {
    int q = tid + 256 * j;
    int c = q >> 4, kc = q & 15;
    *(s8v*)&Ws[c * 128 + ((kc ^ (c & 7)) << 3)] = *(const s8v*)(W2gT + c * 128 + kc * 8);
  }
  __syncthreads();

  s8v a2[2][4];
#pragma unroll
  for (int rt = 0; rt < 2; ++rt) {
    int r = wave * 32 + rt * 16 + rlo;
#pragma unroll
    for (int ks = 0; ks < 4; ++ks)
      a2[rt][ks] = *(const s8v*)&Hs[r * HS_LD + (ks * 4 + khi) * 8];
  }

  f4v acc2[2][8];
#pragma unroll
  for (int rt = 0; rt < 2; ++rt)
#pragma unroll
    for (int ct = 0; ct < 8; ++ct) acc2[rt][ct] = (f4v){0.f, 0.f, 0.f, 0.f};

#pragma unroll
  for (int ks = 0; ks < 4; ++ks) {
#pragma unroll
    for (int ct = 0; ct < 8; ++ct) {
      int c = ct * 16 + rlo;
      int kc = ks * 4 + khi;
      s8v b = *(const s8v*)&Ws[c * 128 + ((kc ^ (c & 7)) << 3)];
      acc2[0][ct] = __builtin_amdgcn_mfma_f32_16x16x32_bf16(a2[0][ks], b, acc2[0][ct], 0, 0, 0);
      acc2[1][ct] = __builtin_amdgcn_mfma_f32_16x16x32_bf16(a2[1][ks], b, acc2[1][ct], 0, 0, 0);
    }
  }

  // row scale by dinv (pre-fold the GCN edge weight's source factor)
  float ddv[2][4];
#pragma unroll
  for (int rt = 0; rt < 2; ++rt)
#pragma unroll
    for (int i = 0; i < 4; ++i) {
      int row = rb + rt * 16 + 4 * khi + i;
      ddv[rt][i] = (row < n) ? dinv[row] : 0.f;
    }

#pragma unroll
  for (int ct = 0; ct < 8; ++ct) {
    int col = ct * 16 + rlo;
#pragma unroll
    for (int rt = 0; rt < 2; ++rt) {
#pragma unroll
      for (int i = 0; i < 4; ++i) {
        int row = rb + rt * 16 + 4 * khi + i;
        if (row < n)
          pq[(long)row * 256 + col] = f2bf(ddv[rt][i] * acc2[rt][ct][i]);
      }
    }
  }
}

// ---------------------------------------------------------------------------
// gather B': pure unweighted row-sum of pq over neighbors (p1' pre-scaled).
// out = dd*(sum_p1' + self_p1') + (sum_p2 + self_p2) + btot; f32 out.
// ---------------------------------------------------------------------------
__global__ __launch_bounds__(256) void gatherB_kernel(
    const ushort* __restrict__ pq, const float* __restrict__ dinv,
    const int* __restrict__ rowptr, const int2* __restrict__ cd,
    const float* __restrict__ btot, float* __restrict__ out, int n) {
  int nd = blockIdx.x * 4 + (threadIdx.x >> 6);
  if (nd >= n) return;
  int lane = threadIdx.x & 63;
  int half = lane >> 5;
  int hl = lane & 31;
  int beg = rowptr[nd], end = rowptr[nd + 1];
  float4 s = make_float4(0.f, 0.f, 0.f, 0.f);
  int j = beg;
  for (; j + 3 < end; j += 4) {
    int s0 = cd[j].x, s1 = cd[j + 1].x, s2 = cd[j + 2].x, s3 = cd[j + 3].x;
    ushort4 v0 = *(const ushort4*)(pq + (long)s0 * 256 + lane * 4);
    ushort4 v1 = *(const ushort4*)(pq + (long)s1 * 256 + lane * 4);
    ushort4 v2 = *(const ushort4*)(pq + (long)s2 * 256 + lane * 4);
    ushort4 v3 = *(const ushort4*)(pq + (long)s3 * 256 + lane * 4);
    s.x += (bf2f(v0.x) + bf2f(v1.x)) + (bf2f(v2.x) + bf2f(v3.x));
    s.y += (bf2f(v0.y) + bf2f(v1.y)) + (bf2f(v2.y) + bf2f(v3.y));
    s.z += (bf2f(v0.z) + bf2f(v1.z)) + (bf2f(v2.z) + bf2f(v3.z));
    s.w += (bf2f(v0.w) + bf2f(v1.w)) + (bf2f(v2.w) + bf2f(v3.w));
  }
  for (; j < end; ++j) {
    int s0 = cd[j].x;
    ushort4 v0 = *(const ushort4*)(pq + (long)s0 * 256 + lane * 4);
    s.x += bf2f(v0.x); s.y += bf2f(v0.y);
    s.z += bf2f(v0.z); s.w += bf2f(v0.w);
  }
  ushort4 u = *(const ushort4*)(pq + (long)nd * 256 + lane * 4);
  float dd = dinv[nd];
  float4 o;
  if (half == 0) {  // GCN: dd*(sum + self), p1' already dinv_src-scaled
    o.x = dd * (s.x + bf2f(u.x));
    o.y = dd * (s.y + bf2f(u.y));
    o.z = dd * (s.z + bf2f(u.z));
    o.w = dd * (s.w + bf2f(u.w));
  } else {          // GIN: sum + self
    o.x = s.x + bf2f(u.x);
    o.y = s.y + bf2f(u.y);
    o.z = s.z + bf2f(u.z);
    o.w = s.w + bf2f(u.w);
  }
  o.x += __shfl_xor(o.x, 32);
  o.y += __shfl_xor(o.y, 32);
  o.z += __shfl_xor(o.z, 32);
  o.w += __shfl_xor(o.w, 32);
  if (half == 0) {
    float4 bt = *(const float4*)(btot + 4 * hl);
    o.x += bt.x; o.y += bt.y; o.z += bt.z; o.w += bt.w;
    *(float4*)(out + (long)nd * D + 4 * hl) = o;
  }
}

// ---------------------------------------------------------------------------
extern "C" void kernel_launch(void* const* d_in, const int* in_sizes, int n_in,
                              void* d_out, int out_size, void* d_ws, size_t ws_size,
                              hipStream_t stream) {
  const float* x   = (const float*)d_in[0];
  const int*   ei  = (const int*)d_in[1];
  const float* gw1 = (const float*)d_in[2];
  const float* gb1 = (const float*)d_in[3];
  const float* gw2 = (const float*)d_in[4];
  const float* gb2 = (const float*)d_in[5];
  const float* iw1 = (const float*)d_in[6];
  const float* ib1 = (const float*)d_in[7];
  const float* iw2 = (const float*)d_in[8];
  const float* ib2 = (const float*)d_in[9];
  const float* lw  = (const float*)d_in[10];
  const float* lb  = (const float*)d_in[11];
  const float* fw  = (const float*)d_in[12];
  const float* fb  = (const float*)d_in[13];
  float* out = (float*)d_out;

  const int n = in_sizes[0] / D;
  const int E = in_sizes[1] / 2;
  const int* src = ei;
  const int* dst = ei + E;
  const int nb = (n + 255) / 256;
  const long ND = (long)n * D;

  char* p = (char*)d_ws;
  auto alloc = [&](size_t bytes) {
    char* r = p;
    p += (bytes + 255) & ~(size_t)255;
    return r;
  };
  int* ideg    = (int*)alloc((size_t)n * 4);
  int* incl    = (int*)alloc((size_t)n * 4);
  int* rowptr  = (int*)alloc((size_t)(n + 1) * 4);
  int* bsum    = (int*)alloc(1024 * 4);
  int* pos     = (int*)alloc((size_t)E * 4);
  int2* cdata  = (int2*)alloc((size_t)E * 8);
  float* dinv  = (float*)alloc((size_t)n * 4);
  float* LF    = (float*)alloc(16384 * 4);
  float* M2i   = (float*)alloc(16384 * 4);
  float* btot  = (float*)alloc(128 * 4);
  float* bgin  = (float*)alloc(128 * 4);
  ushort* xb   = (ushort*)alloc(ND * 2);
  ushort* T1g   = (ushort*)alloc(16384 * 2);
  ushort* WginT = (ushort*)alloc(16384 * 2);
  ushort* W2gT  = (ushort*)alloc(16384 * 2);
  ushort* ab   = (ushort*)alloc(2 * ND * 2);  // gatherA out / gemm1 in
  ushort* pq   = (ushort*)alloc(2 * ND * 2);  // gemm1 out / gatherB in

  hipMemsetAsync(ideg, 0, (size_t)n * 4, stream);

  // front end: degpos | xcvt | LF | gw1-transpose
  megaA_kernel<<<5376, 256, 0, stream>>>(dst, ideg, pos, E, x, xb, ND, lw, fw, LF, gw1, T1g);
  // scan1 | M2i | W2gT | btot
  scanP_kernel<<<nb + 129, 256, 0, stream>>>(ideg, incl, bsum, n, nb, iw2, gw2, LF,
                                             M2i, W2gT, gb2, ib2, lb, fw, fb, btot);
  // scan2 | WginT | bgin
  scan2F_kernel<<<66, 256, 0, stream>>>(bsum, nb, iw1, M2i, WginT, ib1, bgin);
  scan3_kernel<<<nb, 256, 0, stream>>>(ideg, incl, bsum, rowptr, dinv, n, E);
  scatter_kernel<<<2048, 256, 0, stream>>>(src, dst, rowptr, pos, dinv, cdata, E);

  // layer 1 aggregation
  gatherA_kernel<<<(n + 3) / 4, 256, 0, stream>>>(xb, dinv, rowptr, cdata, ab, n);
  // fused GEMMs
  const int nblk = (n + 127) / 128;
  gemm1_kernel<<<dim3(nblk, 2), 256, 0, stream>>>(ab, T1g, WginT, W2gT, gb1, bgin, dinv, pq, n);
  // final aggregation writes output directly
  gatherB_kernel<<<(n + 3) / 4, 256, 0, stream>>>(pq, dinv, rowptr, cdata, btot, out, n);
}

// Round 8
// 370.689 us; speedup vs baseline: 1.0631x; 1.0631x over previous
//
#include <hip/hip_runtime.h>

#define D 128
#define HS_LD 136  // h-tile LDS stride (ushorts): 272B rows, 16B-aligned, 2-way conflicts only

using s8v = __attribute__((ext_vector_type(8))) short;
using f4v = __attribute__((ext_vector_type(4))) float;

__device__ __forceinline__ float bf2f(ushort u) {
  union { uint i; float f; } v; v.i = ((uint)u) << 16; return v.f;
}
__device__ __forceinline__ ushort f2bf(float f) {
  union { float f; uint i; } v; v.f = f;
  uint b = v.i;
  return (ushort)((b + 0x7fffu + ((b >> 16) & 1u)) >> 16);
}

// ---------------------------------------------------------------------------
// megaA: blocks [0,2048) degpos | [2048,5248) xcvt | [5248,5312) LF=lw@fw |
//        [5312,5376) T1g = bf16T(gw1)
// ---------------------------------------------------------------------------
__global__ void megaA_kernel(const int* __restrict__ dst, int* __restrict__ ideg,
                             int* __restrict__ pos, int E,
                             const float* __restrict__ x, ushort* __restrict__ xb, long total,
                             const float* __restrict__ lw, const float* __restrict__ fw,
                             float* __restrict__ LF,
                             const float* __restrict__ gw1, ushort* __restrict__ T1g) {
  int b = blockIdx.x;
  if (b < 2048) {
    int i = b * 256 + threadIdx.x;
    int stride = 2048 * 256;
    for (int e = i; e < E; e += stride)
      pos[e] = atomicAdd(&ideg[dst[e]], 1);
  } else if (b < 5248) {
    long i = ((long)(b - 2048) * 256 + threadIdx.x) * 8;
    long stride = (long)3200 * 256 * 8;
    for (long t = i; t < total; t += stride) {
      float4 v0 = *(const float4*)(x + t);
      float4 v1 = *(const float4*)(x + t + 4);
      s8v u;
      u[0] = (short)f2bf(v0.x); u[1] = (short)f2bf(v0.y);
      u[2] = (short)f2bf(v0.z); u[3] = (short)f2bf(v0.w);
      u[4] = (short)f2bf(v1.x); u[5] = (short)f2bf(v1.y);
      u[6] = (short)f2bf(v1.z); u[7] = (short)f2bf(v1.w);
      *(s8v*)(xb + t) = u;
    }
  } else if (b < 5312) {
    int t = (b - 5248) * 256 + threadIdx.x;
    int r = t >> 7, c = t & 127;
    float s = 0.f;
#pragma unroll 8
    for (int k = 0; k < 128; ++k) s = fmaf(lw[r * 128 + k], fw[k * 128 + c], s);
    LF[r * 128 + c] = s;
  } else {
    int t = (b - 5312) * 256 + threadIdx.x;
    int k = t >> 7, c = t & 127;
    T1g[c * 128 + k] = f2bf(gw1[k * 128 + c]);
  }
}

// ---------------------------------------------------------------------------
// scanP: blocks [0,nb) scan1 | [nb,nb+64) M2i=iw2@LF | [nb+64,nb+128)
//        W2gT=bf16T(gw2@LF) | [nb+128] btot
// ---------------------------------------------------------------------------
__global__ void scanP_kernel(const int* __restrict__ deg, int* __restrict__ incl,
                             int* __restrict__ bsum, int n, int nb,
                             const float* __restrict__ iw2, const float* __restrict__ gw2,
                             const float* __restrict__ LF,
                             float* __restrict__ M2i, ushort* __restrict__ W2gT,
                             const float* __restrict__ gb2, const float* __restrict__ ib2,
                             const float* __restrict__ lb, const float* __restrict__ fw,
                             const float* __restrict__ fb, float* __restrict__ btot) {
  int b = blockIdx.x;
  if (b < nb) {
    __shared__ int tmp[256];
    int t = threadIdx.x;
    int i = b * 256 + t;
    int v = (i < n) ? deg[i] : 0;
    tmp[t] = v;
    __syncthreads();
#pragma unroll
    for (int off = 1; off < 256; off <<= 1) {
      int u = (t >= off) ? tmp[t - off] : 0;
      __syncthreads();
      tmp[t] += u;
      __syncthreads();
    }
    if (i < n) incl[i] = tmp[t];
    if (t == 255) bsum[b] = tmp[255];
  } else if (b < nb + 64) {
    int t = (b - nb) * 256 + threadIdx.x;
    int k = t >> 7, c = t & 127;
    float s = 0.f;
#pragma unroll 8
    for (int j = 0; j < 128; ++j) s = fmaf(iw2[k * 128 + j], LF[j * 128 + c], s);
    M2i[k * 128 + c] = s;
  } else if (b < nb + 128) {
    int t = (b - nb - 64) * 256 + threadIdx.x;
    int k = t >> 7, c = t & 127;
    float s = 0.f;
#pragma unroll 8
    for (int j = 0; j < 128; ++j) s = fmaf(gw2[k * 128 + j], LF[j * 128 + c], s);
    W2gT[c * 128 + k] = f2bf(s);
  } else if (threadIdx.x < 128) {
    int c = threadIdx.x;
    float s = fb[c];
#pragma unroll 8
    for (int j = 0; j < 128; ++j) {
      s = fmaf(gb2[j] + ib2[j], LF[j * 128 + c], s);
      s = fmaf(2.f * lb[j], fw[j * 128 + c], s);
    }
    btot[c] = s;
  }
}

// ---------------------------------------------------------------------------
// scan2F: block 0 scan2 | blocks [1,64] WginT=bf16T(iw1@M2i) | block 65 bgin
// ---------------------------------------------------------------------------
__global__ void scan2F_kernel(int* __restrict__ bsum, int nb,
                              const float* __restrict__ iw1, const float* __restrict__ M2i,
                              ushort* __restrict__ WginT,
                              const float* __restrict__ ib1, float* __restrict__ bgin) {
  int b = blockIdx.x;
  if (b == 0) {
    __shared__ int tmp[256];
    __shared__ int carry_s;
    int t = threadIdx.x;
    if (t == 0) carry_s = 0;
    __syncthreads();
    for (int base = 0; base < nb; base += 256) {
      int v = (base + t < nb) ? bsum[base + t] : 0;
      tmp[t] = v;
      __syncthreads();
#pragma unroll
      for (int off = 1; off < 256; off <<= 1) {
        int u = (t >= off) ? tmp[t - off] : 0;
        __syncthreads();
        tmp[t] += u;
        __syncthreads();
      }
      int inc = tmp[t] + carry_s;
      if (base + t < nb) bsum[base + t] = inc;
      __syncthreads();
      if (t == 255) carry_s = inc;
      __syncthreads();
    }
  } else if (b <= 64) {
    int t = (b - 1) * 256 + threadIdx.x;
    int k = t >> 7, c = t & 127;
    float s = 0.f;
#pragma unroll 8
    for (int j = 0; j < 128; ++j) s = fmaf(iw1[k * 128 + j], M2i[j * 128 + c], s);
    WginT[c * 128 + k] = f2bf(s);
  } else if (threadIdx.x < 128) {
    int c = threadIdx.x;
    float s = 0.f;
#pragma unroll 8
    for (int j = 0; j < 128; ++j) s = fmaf(ib1[j], M2i[j * 128 + c], s);
    bgin[c] = s;
  }
}

__global__ void scan3_kernel(const int* __restrict__ deg, const int* __restrict__ incl,
                             const int* __restrict__ bsum, int* __restrict__ rowptr,
                             float* __restrict__ dinv, int n, int E) {
  int i = blockIdx.x * 256 + threadIdx.x;
  if (i < n) {
    int carry = (blockIdx.x > 0) ? bsum[blockIdx.x - 1] : 0;
    int d = deg[i];
    rowptr[i] = incl[i] - d + carry;
    dinv[i] = rsqrtf((float)d + 1.0f);
  }
  if (i == 0) rowptr[n] = E;
}

// scatter (no atomics): csrc[rowptr[d] + pos[e]] = src[e]
__global__ void scatter_kernel(const int* __restrict__ src, const int* __restrict__ dst,
                               const int* __restrict__ rowptr, const int* __restrict__ pos,
                               int* __restrict__ csrc, int E) {
  int i = blockIdx.x * blockDim.x + threadIdx.x;
  int stride = gridDim.x * blockDim.x;
  for (int e = i; e < E; e += stride)
    csrc[rowptr[dst[e]] + pos[e]] = src[e];
}

// ---------------------------------------------------------------------------
// gather A: wave halves on alternate edges, 4-deep MLP; dinv[s] from the
// L2-resident dinv array; shfl_xor(32) combine; ab[node][256]=[gcn|gin] bf16.
// ---------------------------------------------------------------------------
__global__ __launch_bounds__(256) void gatherA_kernel(
    const ushort* __restrict__ xb, const float* __restrict__ dinv,
    const int* __restrict__ rowptr, const int* __restrict__ csrc,
    ushort* __restrict__ ab, int n) {
  int nd = blockIdx.x * 4 + (threadIdx.x >> 6);
  if (nd >= n) return;
  int lane = threadIdx.x & 63;
  int half = lane >> 5;
  int hl = lane & 31;
  int beg = rowptr[nd], end = rowptr[nd + 1];
  float4 sg = make_float4(0.f, 0.f, 0.f, 0.f);
  float4 sc = make_float4(0.f, 0.f, 0.f, 0.f);
  int j = beg + half;
  for (; j + 6 < end; j += 8) {
    int s0 = csrc[j], s1 = csrc[j + 2], s2 = csrc[j + 4], s3 = csrc[j + 6];
    float w0 = dinv[s0], w1 = dinv[s1], w2 = dinv[s2], w3 = dinv[s3];
    ushort4 v0 = *(const ushort4*)(xb + (long)s0 * D + 4 * hl);
    ushort4 v1 = *(const ushort4*)(xb + (long)s1 * D + 4 * hl);
    ushort4 v2 = *(const ushort4*)(xb + (long)s2 * D + 4 * hl);
    ushort4 v3 = *(const ushort4*)(xb + (long)s3 * D + 4 * hl);
    float a0 = bf2f(v0.x), a1 = bf2f(v0.y), a2 = bf2f(v0.z), a3 = bf2f(v0.w);
    sg.x += a0; sg.y += a1; sg.z += a2; sg.w += a3;
    sc.x = fmaf(w0, a0, sc.x); sc.y = fmaf(w0, a1, sc.y);
    sc.z = fmaf(w0, a2, sc.z); sc.w = fmaf(w0, a3, sc.w);
    a0 = bf2f(v1.x); a1 = bf2f(v1.y); a2 = bf2f(v1.z); a3 = bf2f(v1.w);
    sg.x += a0; sg.y += a1; sg.z += a2; sg.w += a3;
    sc.x = fmaf(w1, a0, sc.x); sc.y = fmaf(w1, a1, sc.y);
    sc.z = fmaf(w1, a2, sc.z); sc.w = fmaf(w1, a3, sc.w);
    a0 = bf2f(v2.x); a1 = bf2f(v2.y); a2 = bf2f(v2.z); a3 = bf2f(v2.w);
    sg.x += a0; sg.y += a1; sg.z += a2; sg.w += a3;
    sc.x = fmaf(w2, a0, sc.x); sc.y = fmaf(w2, a1, sc.y);
    sc.z = fmaf(w2, a2, sc.z); sc.w = fmaf(w2, a3, sc.w);
    a0 = bf2f(v3.x); a1 = bf2f(v3.y); a2 = bf2f(v3.z); a3 = bf2f(v3.w);
    sg.x += a0; sg.y += a1; sg.z += a2; sg.w += a3;
    sc.x = fmaf(w3, a0, sc.x); sc.y = fmaf(w3, a1, sc.y);
    sc.z = fmaf(w3, a2, sc.z); sc.w = fmaf(w3, a3, sc.w);
  }
  for (; j < end; j += 2) {
    int s0 = csrc[j];
    float w0 = dinv[s0];
    ushort4 v0 = *(const ushort4*)(xb + (long)s0 * D + 4 * hl);
    float a0 = bf2f(v0.x), a1 = bf2f(v0.y), a2 = bf2f(v0.z), a3 = bf2f(v0.w);
    sg.x += a0; sg.y += a1; sg.z += a2; sg.w += a3;
    sc.x = fmaf(w0, a0, sc.x); sc.y = fmaf(w0, a1, sc.y);
    sc.z = fmaf(w0, a2, sc.z); sc.w = fmaf(w0, a3, sc.w);
  }
  sg.x += __shfl_xor(sg.x, 32); sg.y += __shfl_xor(sg.y, 32);
  sg.z += __shfl_xor(sg.z, 32); sg.w += __shfl_xor(sg.w, 32);
  sc.x += __shfl_xor(sc.x, 32); sc.y += __shfl_xor(sc.y, 32);
  sc.z += __shfl_xor(sc.z, 32); sc.w += __shfl_xor(sc.w, 32);

  ushort4 us = *(const ushort4*)(xb + (long)nd * D + 4 * hl);
  float x0 = bf2f(us.x), x1 = bf2f(us.y), x2 = bf2f(us.z), x3 = bf2f(us.w);
  float dd = dinv[nd];
  ushort4 o;
  if (half == 0) {
    o.x = f2bf(dd * (sc.x + dd * x0));
    o.y = f2bf(dd * (sc.y + dd * x1));
    o.z = f2bf(dd * (sc.z + dd * x2));
    o.w = f2bf(dd * (sc.w + dd * x3));
    *(ushort4*)(ab + (long)nd * 256 + 4 * hl) = o;
  } else {
    o.x = f2bf(x0 + sg.x);
    o.y = f2bf(x1 + sg.y);
    o.z = f2bf(x2 + sg.z);
    o.w = f2bf(x3 + sg.w);
    *(ushort4*)(ab + (long)nd * 256 + 128 + 4 * hl) = o;
  }
}

// ---------------------------------------------------------------------------
// gemm1': y=0 (GCN): h = relu(Agcn@T1g^T + gb1); p1' = dinv_row * (h @ W2gT^T).
//         y=1 (GIN): p2 = Agin@WginT^T + bgin.
// Output pq[node][256] = [p1' | p2] bf16.
// ---------------------------------------------------------------------------
__global__ __launch_bounds__(256) void gemm1_kernel(
    const ushort* __restrict__ ab,
    const ushort* __restrict__ T1g, const ushort* __restrict__ WginT,
    const ushort* __restrict__ W2gT,
    const float* __restrict__ gb1, const float* __restrict__ bgin,
    const float* __restrict__ dinv,
    ushort* __restrict__ pq, int n) {
  __shared__ ushort Ws[128 * 128];
  __shared__ ushort Hs[128 * HS_LD];
  const int y = blockIdx.y;
  const int tid = threadIdx.x;
  const int wave = tid >> 6, lane = tid & 63;
  const int rlo = lane & 15, khi = lane >> 4;
  const int rb = blockIdx.x * 128 + wave * 32;

  s8v a[2][4];
#pragma unroll
  for (int rt = 0; rt < 2; ++rt) {
    int row = rb + rt * 16 + rlo;
    row = row < n ? row : n - 1;
    const ushort* p = ab + (long)row * 256 + y * 128 + khi * 8;
#pragma unroll
    for (int ks = 0; ks < 4; ++ks) a[rt][ks] = *(const s8v*)(p + ks * 32);
  }

  {
    const ushort* W = y ? WginT : T1g;
#pragma unroll
    for (int j = 0; j < 8; ++j) {
      int q = tid + 256 * j;
      int c = q >> 4, kc = q & 15;
      *(s8v*)&Ws[c * 128 + ((kc ^ (c & 7)) << 3)] = *(const s8v*)(W + c * 128 + kc * 8);
    }
  }
  __syncthreads();

  f4v acc[2][8];
#pragma unroll
  for (int rt = 0; rt < 2; ++rt)
#pragma unroll
    for (int ct = 0; ct < 8; ++ct) acc[rt][ct] = (f4v){0.f, 0.f, 0.f, 0.f};

#pragma unroll
  for (int ks = 0; ks < 4; ++ks) {
#pragma unroll
    for (int ct = 0; ct < 8; ++ct) {
      int c = ct * 16 + rlo;
      int kc = ks * 4 + khi;
      s8v b = *(const s8v*)&Ws[c * 128 + ((kc ^ (c & 7)) << 3)];
      acc[0][ct] = __builtin_amdgcn_mfma_f32_16x16x32_bf16(a[0][ks], b, acc[0][ct], 0, 0, 0);
      acc[1][ct] = __builtin_amdgcn_mfma_f32_16x16x32_bf16(a[1][ks], b, acc[1][ct], 0, 0, 0);
    }
  }

  if (y == 1) {
#pragma unroll
    for (int ct = 0; ct < 8; ++ct) {
      int col = ct * 16 + rlo;
      float bb = bgin[col];
#pragma unroll
      for (int rt = 0; rt < 2; ++rt) {
#pragma unroll
        for (int i = 0; i < 4; ++i) {
          int row = rb + rt * 16 + 4 * khi + i;
          if (row < n)
            pq[(long)row * 256 + 128 + col] = f2bf(acc[rt][ct][i] + bb);
        }
      }
    }
    return;
  }

  // ---- GCN stage 2 ----
  __syncthreads();
#pragma unroll
  for (int ct = 0; ct < 8; ++ct) {
    int col = ct * 16 + rlo;
    float bb = gb1[col];
#pragma unroll
    for (int rt = 0; rt < 2; ++rt) {
#pragma unroll
      for (int i = 0; i < 4; ++i) {
        int r = wave * 32 + rt * 16 + 4 * khi + i;
        Hs[r * HS_LD + col] = f2bf(fmaxf(acc[rt][ct][i] + bb, 0.f));
      }
    }
  }
#pragma unroll
  for (int j = 0; j < 8; ++j) {
    int q = tid + 256 * j;
    int c = q >> 4, kc = q & 15;
    *(s8v*)&Ws[c * 128 + ((kc ^ (c & 7)) << 3)] = *(const s8v*)(W2gT + c * 128 + kc * 8);
  }
  __syncthreads();

  s8v a2[2][4];
#pragma unroll
  for (int rt = 0; rt < 2; ++rt) {
    int r = wave * 32 + rt * 16 + rlo;
#pragma unroll
    for (int ks = 0; ks < 4; ++ks)
      a2[rt][ks] = *(const s8v*)&Hs[r * HS_LD + (ks * 4 + khi) * 8];
  }

  f4v acc2[2][8];
#pragma unroll
  for (int rt = 0; rt < 2; ++rt)
#pragma unroll
    for (int ct = 0; ct < 8; ++ct) acc2[rt][ct] = (f4v){0.f, 0.f, 0.f, 0.f};

#pragma unroll
  for (int ks = 0; ks < 4; ++ks) {
#pragma unroll
    for (int ct = 0; ct < 8; ++ct) {
      int c = ct * 16 + rlo;
      int kc = ks * 4 + khi;
      s8v b = *(const s8v*)&Ws[c * 128 + ((kc ^ (c & 7)) << 3)];
      acc2[0][ct] = __builtin_amdgcn_mfma_f32_16x16x32_bf16(a2[0][ks], b, acc2[0][ct], 0, 0, 0);
      acc2[1][ct] = __builtin_amdgcn_mfma_f32_16x16x32_bf16(a2[1][ks], b, acc2[1][ct], 0, 0, 0);
    }
  }

  float ddv[2][4];
#pragma unroll
  for (int rt = 0; rt < 2; ++rt)
#pragma unroll
    for (int i = 0; i < 4; ++i) {
      int row = rb + rt * 16 + 4 * khi + i;
      ddv[rt][i] = (row < n) ? dinv[row] : 0.f;
    }

#pragma unroll
  for (int ct = 0; ct < 8; ++ct) {
    int col = ct * 16 + rlo;
#pragma unroll
    for (int rt = 0; rt < 2; ++rt) {
#pragma unroll
      for (int i = 0; i < 4; ++i) {
        int row = rb + rt * 16 + 4 * khi + i;
        if (row < n)
          pq[(long)row * 256 + col] = f2bf(ddv[rt][i] * acc2[rt][ct][i]);
      }
    }
  }
}

// ---------------------------------------------------------------------------
// gather B': pure unweighted row-sum of pq over neighbors (p1' pre-scaled).
// out = dd*(sum_p1' + self_p1') + (sum_p2 + self_p2) + btot; f32 out.
// ---------------------------------------------------------------------------
__global__ __launch_bounds__(256) void gatherB_kernel(
    const ushort* __restrict__ pq, const float* __restrict__ dinv,
    const int* __restrict__ rowptr, const int* __restrict__ csrc,
    const float* __restrict__ btot, float* __restrict__ out, int n) {
  int nd = blockIdx.x * 4 + (threadIdx.x >> 6);
  if (nd >= n) return;
  int lane = threadIdx.x & 63;
  int half = lane >> 5;
  int hl = lane & 31;
  int beg = rowptr[nd], end = rowptr[nd + 1];
  float4 s = make_float4(0.f, 0.f, 0.f, 0.f);
  int j = beg;
  for (; j + 3 < end; j += 4) {
    int s0 = csrc[j], s1 = csrc[j + 1], s2 = csrc[j + 2], s3 = csrc[j + 3];
    ushort4 v0 = *(const ushort4*)(pq + (long)s0 * 256 + lane * 4);
    ushort4 v1 = *(const ushort4*)(pq + (long)s1 * 256 + lane * 4);
    ushort4 v2 = *(const ushort4*)(pq + (long)s2 * 256 + lane * 4);
    ushort4 v3 = *(const ushort4*)(pq + (long)s3 * 256 + lane * 4);
    s.x += (bf2f(v0.x) + bf2f(v1.x)) + (bf2f(v2.x) + bf2f(v3.x));
    s.y += (bf2f(v0.y) + bf2f(v1.y)) + (bf2f(v2.y) + bf2f(v3.y));
    s.z += (bf2f(v0.z) + bf2f(v1.z)) + (bf2f(v2.z) + bf2f(v3.z));
    s.w += (bf2f(v0.w) + bf2f(v1.w)) + (bf2f(v2.w) + bf2f(v3.w));
  }
  for (; j < end; ++j) {
    int s0 = csrc[j];
    ushort4 v0 = *(const ushort4*)(pq + (long)s0 * 256 + lane * 4);
    s.x += bf2f(v0.x); s.y += bf2f(v0.y);
    s.z += bf2f(v0.z); s.w += bf2f(v0.w);
  }
  ushort4 u = *(const ushort4*)(pq + (long)nd * 256 + lane * 4);
  float dd = dinv[nd];
  float4 o;
  if (half == 0) {  // GCN: dd*(sum + self), p1' already dinv_src-scaled
    o.x = dd * (s.x + bf2f(u.x));
    o.y = dd * (s.y + bf2f(u.y));
    o.z = dd * (s.z + bf2f(u.z));
    o.w = dd * (s.w + bf2f(u.w));
  } else {          // GIN: sum + self
    o.x = s.x + bf2f(u.x);
    o.y = s.y + bf2f(u.y);
    o.z = s.z + bf2f(u.z);
    o.w = s.w + bf2f(u.w);
  }
  o.x += __shfl_xor(o.x, 32);
  o.y += __shfl_xor(o.y, 32);
  o.z += __shfl_xor(o.z, 32);
  o.w += __shfl_xor(o.w, 32);
  if (half == 0) {
    float4 bt = *(const float4*)(btot + 4 * hl);
    o.x += bt.x; o.y += bt.y; o.z += bt.z; o.w += bt.w;
    *(float4*)(out + (long)nd * D + 4 * hl) = o;
  }
}

// ---------------------------------------------------------------------------
extern "C" void kernel_launch(void* const* d_in, const int* in_sizes, int n_in,
                              void* d_out, int out_size, void* d_ws, size_t ws_size,
                              hipStream_t stream) {
  const float* x   = (const float*)d_in[0];
  const int*   ei  = (const int*)d_in[1];
  const float* gw1 = (const float*)d_in[2];
  const float* gb1 = (const float*)d_in[3];
  const float* gw2 = (const float*)d_in[4];
  const float* gb2 = (const float*)d_in[5];
  const float* iw1 = (const float*)d_in[6];
  const float* ib1 = (const float*)d_in[7];
  const float* iw2 = (const float*)d_in[8];
  const float* ib2 = (const float*)d_in[9];
  const float* lw  = (const float*)d_in[10];
  const float* lb  = (const float*)d_in[11];
  const float* fw  = (const float*)d_in[12];
  const float* fb  = (const float*)d_in[13];
  float* out = (float*)d_out;

  const int n = in_sizes[0] / D;
  const int E = in_sizes[1] / 2;
  const int* src = ei;
  const int* dst = ei + E;
  const int nb = (n + 255) / 256;
  const long ND = (long)n * D;

  char* p = (char*)d_ws;
  auto alloc = [&](size_t bytes) {
    char* r = p;
    p += (bytes + 255) & ~(size_t)255;
    return r;
  };
  int* ideg    = (int*)alloc((size_t)n * 4);
  int* incl    = (int*)alloc((size_t)n * 4);
  int* rowptr  = (int*)alloc((size_t)(n + 1) * 4);
  int* bsum    = (int*)alloc(1024 * 4);
  int* pos     = (int*)alloc((size_t)E * 4);
  int* csrc    = (int*)alloc((size_t)E * 4);
  float* dinv  = (float*)alloc((size_t)n * 4);
  float* LF    = (float*)alloc(16384 * 4);
  float* M2i   = (float*)alloc(16384 * 4);
  float* btot  = (float*)alloc(128 * 4);
  float* bgin  = (float*)alloc(128 * 4);
  ushort* xb   = (ushort*)alloc(ND * 2);
  ushort* T1g   = (ushort*)alloc(16384 * 2);
  ushort* WginT = (ushort*)alloc(16384 * 2);
  ushort* W2gT  = (ushort*)alloc(16384 * 2);
  ushort* ab   = (ushort*)alloc(2 * ND * 2);  // gatherA out / gemm1 in
  ushort* pq   = (ushort*)alloc(2 * ND * 2);  // gemm1 out / gatherB in

  hipMemsetAsync(ideg, 0, (size_t)n * 4, stream);

  // front end: degpos | xcvt | LF | gw1-transpose
  megaA_kernel<<<5376, 256, 0, stream>>>(dst, ideg, pos, E, x, xb, ND, lw, fw, LF, gw1, T1g);
  // scan1 | M2i | W2gT | btot
  scanP_kernel<<<nb + 129, 256, 0, stream>>>(ideg, incl, bsum, n, nb, iw2, gw2, LF,
                                             M2i, W2gT, gb2, ib2, lb, fw, fb, btot);
  // scan2 | WginT | bgin
  scan2F_kernel<<<66, 256, 0, stream>>>(bsum, nb, iw1, M2i, WginT, ib1, bgin);
  scan3_kernel<<<nb, 256, 0, stream>>>(ideg, incl, bsum, rowptr, dinv, n, E);
  scatter_kernel<<<2048, 256, 0, stream>>>(src, dst, rowptr, pos, csrc, E);

  // layer 1 aggregation
  gatherA_kernel<<<(n + 3) / 4, 256, 0, stream>>>(xb, dinv, rowptr, csrc, ab, n);
  // fused GEMMs
  const int nblk = (n + 127) / 128;
  gemm1_kernel<<<dim3(nblk, 2), 256, 0, stream>>>(ab, T1g, WginT, W2gT, gb1, bgin, dinv, pq, n);
  // final aggregation writes output directly
  gatherB_kernel<<<(n + 3) / 4, 256, 0, stream>>>(pq, dinv, rowptr, csrc, btot, out, n);
}